// Round 1
// baseline (879.841 us; speedup 1.0000x reference)
//
#include <hip/hip_runtime.h>

typedef unsigned short u16;
typedef unsigned int   u32;

#define HIMG 56
#define WIMG 56
#define CH   128
#define NHEADS 4
#define WSZ  7
#define SSH  3
#define PP   10
#define HIDD 512
#define NWIN 49          // window tokens
#define NTOK 59          // P + NWIN
#define BWIN 2048        // B * NW
#define DH   32          // head dim
#define MWIN 120832      // BWIN * NTOK
#define MPIX 100352      // B * 56 * 56

__device__ __forceinline__ u16 f2b(float f) {
  u32 u = __float_as_uint(f);
  u += 0x7fffu + ((u >> 16) & 1u);
  return (u16)(u >> 16);
}
__device__ __forceinline__ float blo(u32 w) { return __uint_as_float(w << 16); }
__device__ __forceinline__ float bhi(u32 w) { return __uint_as_float(w & 0xffff0000u); }

// ---------------------------------------------------------------------------
// Fold LoRA (rank 4, scale 1.0) into effective weights:
// out = [wqkv | wproj | wfc1 | wfc2] contiguous fp32.
// ---------------------------------------------------------------------------
__global__ void fuse_all_kernel(
    const float* __restrict__ qw,  const float* __restrict__ qa,  const float* __restrict__ qb,
    const float* __restrict__ pw,  const float* __restrict__ pa,  const float* __restrict__ pb,
    const float* __restrict__ f1w, const float* __restrict__ f1a, const float* __restrict__ f1b,
    const float* __restrict__ f2w, const float* __restrict__ f2a, const float* __restrict__ f2b2,
    float* __restrict__ out)
{
  int idx = blockIdx.x * 256 + threadIdx.x;
  if (idx >= 196608) return;
  const float *w, *la, *lb; int Nc, base;
  if (idx < 49152)       { w = qw;  la = qa;  lb = qb;   Nc = 384; base = 0; }
  else if (idx < 65536)  { w = pw;  la = pa;  lb = pb;   Nc = 128; base = 49152; }
  else if (idx < 131072) { w = f1w; la = f1a; lb = f1b;  Nc = 512; base = 65536; }
  else                   { w = f2w; la = f2a; lb = f2b2; Nc = 128; base = 131072; }
  const int li = idx - base;
  const int i = li / Nc, j = li - i * Nc;
  float s = w[li];
  #pragma unroll
  for (int r = 0; r < 4; ++r) s += la[i * 4 + r] * lb[r * Nc + j];
  out[idx] = s;
}

// ---------------------------------------------------------------------------
// LN1 + roll(-3,-3) + window partition + prompt concat  ->  t (MWIN x 128) bf16
// One 64-lane wave per token (4 tokens / 256-thread block).
// ---------------------------------------------------------------------------
__global__ __launch_bounds__(256) void ln1_gather_kernel(
    const float* __restrict__ x, const float* __restrict__ prompts,
    const float* __restrict__ g, const float* __restrict__ bb,
    u16* __restrict__ t)
{
  const int tok  = blockIdx.x * 4 + (threadIdx.x >> 6);
  const int lane = threadIdx.x & 63;
  const int b_ = tok / NTOK, n = tok - b_ * NTOK;
  u32* dst = (u32*)(t + (size_t)tok * CH) + lane;   // lane writes 2 bf16
  if (n < PP) {
    const int b = b_ >> 6;
    const float2 v = *(const float2*)(prompts + ((size_t)b * PP + n) * CH + lane * 2);
    *dst = (u32)f2b(v.x) | ((u32)f2b(v.y) << 16);
    return;
  }
  const int w  = b_ & 63;
  const int wi = n - PP;
  const int hr = (w >> 3) * WSZ + wi / WSZ;
  const int wc = (w & 7) * WSZ + wi % WSZ;
  const int hs  = (hr + SSH) % HIMG;
  const int ws2 = (wc + SSH) % WIMG;
  const float2 v = *(const float2*)(x + ((size_t)(b_ >> 6) * (HIMG * WIMG) + hs * WIMG + ws2) * CH + lane * 2);
  float s = v.x + v.y, s2 = v.x * v.x + v.y * v.y;
  #pragma unroll
  for (int o = 32; o > 0; o >>= 1) { s += __shfl_xor(s, o); s2 += __shfl_xor(s2, o); }
  const float mean = s * (1.0f / CH);
  const float inv  = rsqrtf(s2 * (1.0f / CH) - mean * mean + 1e-5f);
  const float2 gg = *(const float2*)(g  + lane * 2);
  const float2 bv = *(const float2*)(bb + lane * 2);
  const float o0 = (v.x - mean) * inv * gg.x + bv.x;
  const float o1 = (v.y - mean) * inv * gg.y + bv.y;
  *dst = (u32)f2b(o0) | ((u32)f2b(o1) << 16);
}

// ---------------------------------------------------------------------------
// LN2: x1 (fp32) -> m (bf16)
// ---------------------------------------------------------------------------
__global__ __launch_bounds__(256) void ln2_kernel(
    const float* __restrict__ x1, const float* __restrict__ g,
    const float* __restrict__ bb, u16* __restrict__ out)
{
  const int tok  = blockIdx.x * 4 + (threadIdx.x >> 6);
  const int lane = threadIdx.x & 63;
  const float2 v = *(const float2*)(x1 + (size_t)tok * CH + lane * 2);
  float s = v.x + v.y, s2 = v.x * v.x + v.y * v.y;
  #pragma unroll
  for (int o = 32; o > 0; o >>= 1) { s += __shfl_xor(s, o); s2 += __shfl_xor(s2, o); }
  const float mean = s * (1.0f / CH);
  const float inv  = rsqrtf(s2 * (1.0f / CH) - mean * mean + 1e-5f);
  const float2 gg = *(const float2*)(g  + lane * 2);
  const float2 bv = *(const float2*)(bb + lane * 2);
  const float o0 = (v.x - mean) * inv * gg.x + bv.x;
  const float o1 = (v.y - mean) * inv * gg.y + bv.y;
  u32* dst = (u32*)(out + (size_t)tok * CH) + lane;
  *dst = (u32)f2b(o0) | ((u32)f2b(o1) << 16);
}

// ---------------------------------------------------------------------------
// GEMM: C[M,NCOLT] = A[M,KTOT](bf16) * W[KTOT,NCOLT](f32) + bias, + epilogue
// Tile 128x64, 256 threads, per-thread 8x4; A staged raw bf16 (row stride 136
// -> 16B-aligned rows; inner-loop reads are 4-address broadcast, conflict-free).
// MODE 0: store bf16 (qkv)       MODE 2: GELU(exact) -> bf16 (fc1)
// MODE 1: window-reverse + unroll + x residual -> f32 (proj -> x1)
// MODE 3: + x1 residual -> f32 (fc2 -> d_out)
// ---------------------------------------------------------------------------
template<int KTOT, int NCOLT, int MODE>
__global__ __launch_bounds__(256) void gemm_kernel(
    const u16* __restrict__ A, const float* __restrict__ W,
    const float* __restrict__ bias, const float* __restrict__ aux,
    float* __restrict__ outf, u16* __restrict__ outb)
{
  __shared__ u16   a_s[128][136];
  __shared__ float w_s[128][64];
  const int tid = threadIdx.x;
  const int ty = tid >> 4, tx = tid & 15;
  const long rowbase = (long)blockIdx.x * 128;
  const int  colbase = blockIdx.y * 64;
  float acc[8][4];
  #pragma unroll
  for (int i = 0; i < 8; ++i)
    #pragma unroll
    for (int j = 0; j < 4; ++j) acc[i][j] = 0.f;

  for (int kb = 0; kb < KTOT; kb += 128) {
    {
      const int r0 = tid >> 4;
      const int kc = (tid & 15) * 8;
      #pragma unroll
      for (int p = 0; p < 8; ++p) {
        const int r = r0 + p * 16;
        uint4 v = *(const uint4*)(A + (rowbase + r) * KTOT + kb + kc);
        *(uint4*)&a_s[r][kc] = v;
      }
    }
    {
      const int k0 = tid >> 4;
      const int c4 = (tid & 15) * 4;
      #pragma unroll
      for (int p = 0; p < 8; ++p) {
        const int k = k0 + p * 16;
        float4 v = *(const float4*)(W + (long)(kb + k) * NCOLT + colbase + c4);
        *(float4*)&w_s[k][c4] = v;
      }
    }
    __syncthreads();
    for (int k8 = 0; k8 < 128; k8 += 8) {
      uint4 au[8];
      #pragma unroll
      for (int i = 0; i < 8; ++i) au[i] = *(const uint4*)&a_s[ty + i * 16][k8];
      #pragma unroll
      for (int kk = 0; kk < 8; ++kk) {
        const float4 wv = *(const float4*)&w_s[k8 + kk][tx * 4];
        #pragma unroll
        for (int i = 0; i < 8; ++i) {
          const u32 word = ((const u32*)&au[i])[kk >> 1];
          const float av = (kk & 1) ? bhi(word) : blo(word);
          acc[i][0] += av * wv.x; acc[i][1] += av * wv.y;
          acc[i][2] += av * wv.z; acc[i][3] += av * wv.w;
        }
      }
    }
    __syncthreads();
  }

  const int c0 = colbase + tx * 4;
  const float4 bsv = *(const float4*)(bias + c0);
  #pragma unroll
  for (int i = 0; i < 8; ++i) {
    const long m = rowbase + ty + i * 16;
    float v0 = acc[i][0] + bsv.x;
    float v1 = acc[i][1] + bsv.y;
    float v2 = acc[i][2] + bsv.z;
    float v3 = acc[i][3] + bsv.w;
    if (MODE == 0) {
      *(ushort4*)(outb + m * NCOLT + c0) = make_ushort4(f2b(v0), f2b(v1), f2b(v2), f2b(v3));
    } else if (MODE == 2) {
      const float k = 0.70710678118654752f;
      v0 = 0.5f * v0 * (1.f + erff(v0 * k));
      v1 = 0.5f * v1 * (1.f + erff(v1 * k));
      v2 = 0.5f * v2 * (1.f + erff(v2 * k));
      v3 = 0.5f * v3 * (1.f + erff(v3 * k));
      *(ushort4*)(outb + m * NCOLT + c0) = make_ushort4(f2b(v0), f2b(v1), f2b(v2), f2b(v3));
    } else if (MODE == 1) {
      const int mi = (int)m;
      const int b_ = mi / NWIN, wi = mi - b_ * NWIN;
      const int w  = b_ & 63;
      const int hr = (w >> 3) * WSZ + wi / WSZ;
      const int wc = (w & 7) * WSZ + wi % WSZ;
      const int hf = (hr + SSH) % HIMG;
      const int wf = (wc + SSH) % WIMG;
      const long o = ((long)(b_ >> 6) * (HIMG * WIMG) + hf * WIMG + wf) * CH + c0;
      const float4 ax = *(const float4*)(aux + o);
      *(float4*)(outf + o) = make_float4(v0 + ax.x, v1 + ax.y, v2 + ax.z, v3 + ax.w);
    } else {
      const long o = m * CH + c0;
      const float4 ax = *(const float4*)(aux + o);
      *(float4*)(outf + o) = make_float4(v0 + ax.x, v1 + ax.y, v2 + ax.z, v3 + ax.w);
    }
  }
}

// ---------------------------------------------------------------------------
// Fused window attention: one block per (window, head).
// QK^T (queries n>=P only) + rel-pos bias + shift mask + softmax + @V.
// ---------------------------------------------------------------------------
__global__ __launch_bounds__(256) void attn_kernel(
    const u16* __restrict__ qkv, const float* __restrict__ rpb,
    u16* __restrict__ attn_out)
{
  __shared__ float q_s[NWIN][DH];
  __shared__ float k_s[NTOK][DH];
  __shared__ float v_s[NTOK][DH];
  __shared__ float S[NWIN][NTOK + 1];
  const int blk = blockIdx.x;
  const int b_ = blk >> 2;
  const int h  = blk & 3;
  const int tid = threadIdx.x;
  const u16* base = qkv + (long)b_ * NTOK * 384 + h * DH;

  for (int idx = tid; idx < NTOK * 4; idx += 256) {
    const int n = idx >> 2, d8 = (idx & 3) * 8;
    const u16* p = base + (long)n * 384;
    const uint4 kv = *(const uint4*)(p + 128 + d8);
    const uint4 vv = *(const uint4*)(p + 256 + d8);
    const u32* kw = (const u32*)&kv; const u32* vw = (const u32*)&vv;
    #pragma unroll
    for (int t2 = 0; t2 < 4; ++t2) {
      k_s[n][d8 + t2 * 2]     = blo(kw[t2]);
      k_s[n][d8 + t2 * 2 + 1] = bhi(kw[t2]);
      v_s[n][d8 + t2 * 2]     = blo(vw[t2]);
      v_s[n][d8 + t2 * 2 + 1] = bhi(vw[t2]);
    }
    if (n >= PP) {
      const uint4 qv = *(const uint4*)(p + d8);
      const u32* qw = (const u32*)&qv;
      #pragma unroll
      for (int t2 = 0; t2 < 4; ++t2) {
        q_s[n - PP][d8 + t2 * 2]     = blo(qw[t2]);
        q_s[n - PP][d8 + t2 * 2 + 1] = bhi(qw[t2]);
      }
    }
  }
  __syncthreads();

  const int w  = b_ & 63;
  const int wh = w >> 3, ww = w & 7;
  const float scale = 0.17677669529663687f;   // 32^-0.5
  for (int idx = tid; idx < NWIN * NTOK; idx += 256) {
    const int i = idx / NTOK, j = idx - i * NTOK;
    float s = 0.f;
    #pragma unroll
    for (int d0 = 0; d0 < DH; d0 += 4) {
      const float4 qa = *(const float4*)&q_s[i][d0];
      const float4 kb = *(const float4*)&k_s[j][d0];
      s += qa.x * kb.x + qa.y * kb.y + qa.z * kb.z + qa.w * kb.w;
    }
    s *= scale;
    if (j >= PP) {
      const int jw = j - PP;
      const int ih = i / 7, iw2 = i - ih * 7, jh = jw / 7, jw2 = jw - jh * 7;
      s += rpb[((ih - jh + 6) * 13 + (iw2 - jw2 + 6)) * NHEADS + h];
      const int mi = 3 * ((wh == 7) ? (ih < 4 ? 1 : 2) : 0) + ((ww == 7) ? (iw2 < 4 ? 1 : 2) : 0);
      const int mj = 3 * ((wh == 7) ? (jh < 4 ? 1 : 2) : 0) + ((ww == 7) ? (jw2 < 4 ? 1 : 2) : 0);
      if (mi != mj) s -= 100.f;
    }
    S[i][j] = s;
  }
  __syncthreads();

  if (tid < NWIN * 4) {               // 4 lanes per row, aligned groups
    const int i = tid >> 2, qq = tid & 3;
    float mx = -1e30f;
    for (int j = qq; j < NTOK; j += 4) mx = fmaxf(mx, S[i][j]);
    mx = fmaxf(mx, __shfl_xor(mx, 1));
    mx = fmaxf(mx, __shfl_xor(mx, 2));
    float sum = 0.f;
    for (int j = qq; j < NTOK; j += 4) { const float e = __expf(S[i][j] - mx); S[i][j] = e; sum += e; }
    sum += __shfl_xor(sum, 1);
    sum += __shfl_xor(sum, 2);
    const float inv = 1.0f / sum;
    for (int j = qq; j < NTOK; j += 4) S[i][j] *= inv;
  }
  __syncthreads();

  for (int idx = tid; idx < NWIN * 8; idx += 256) {
    const int i = idx >> 3, d4 = (idx & 7) * 4;
    float4 o = make_float4(0.f, 0.f, 0.f, 0.f);
    for (int j = 0; j < NTOK; ++j) {
      const float sv = S[i][j];
      const float4 vv = *(const float4*)&v_s[j][d4];
      o.x += sv * vv.x; o.y += sv * vv.y; o.z += sv * vv.z; o.w += sv * vv.w;
    }
    u16* dst = attn_out + ((long)b_ * NWIN + i) * CH + h * DH + d4;
    *(ushort4*)dst = make_ushort4(f2b(o.x), f2b(o.y), f2b(o.z), f2b(o.w));
  }
}

// ---------------------------------------------------------------------------
extern "C" void kernel_launch(void* const* d_in, const int* in_sizes, int n_in,
                              void* d_out, int out_size, void* d_ws, size_t ws_size,
                              hipStream_t stream)
{
  const float* x       = (const float*)d_in[0];
  const float* prompts = (const float*)d_in[1];
  const float* n1g     = (const float*)d_in[2];
  const float* n1b     = (const float*)d_in[3];
  const float* qkv_w   = (const float*)d_in[4];
  const float* qkv_b   = (const float*)d_in[5];
  const float* qkv_la  = (const float*)d_in[6];
  const float* qkv_lb  = (const float*)d_in[7];
  const float* rpb     = (const float*)d_in[8];
  const float* proj_w  = (const float*)d_in[9];
  const float* proj_b  = (const float*)d_in[10];
  const float* proj_la = (const float*)d_in[11];
  const float* proj_lb = (const float*)d_in[12];
  const float* n2g     = (const float*)d_in[13];
  const float* n2b     = (const float*)d_in[14];
  const float* fc1_w   = (const float*)d_in[15];
  const float* fc1_b   = (const float*)d_in[16];
  const float* fc1_la  = (const float*)d_in[17];
  const float* fc1_lb  = (const float*)d_in[18];
  const float* fc2_w   = (const float*)d_in[19];
  const float* fc2_b   = (const float*)d_in[20];
  const float* fc2_la  = (const float*)d_in[21];
  const float* fc2_lb  = (const float*)d_in[22];

  // workspace layout (regions reused across dead ranges):
  //  [0, 786432)                 4 fused weight matrices (fp32)
  //  regA: t (bf16, 30.9MB)  -> attn_out (bf16, 25.7MB) -> m (bf16, 25.7MB)
  //  regB: qkv (bf16, 92.8MB) -> x1 (fp32, 51.4MB)
  //  regC: h (bf16, 102.8MB)
  // total 227,278,848 bytes
  char* ws = (char*)d_ws;
  float* wqkv  = (float*)ws;
  float* wproj = wqkv + 128 * 384;
  float* wfc1  = wproj + 128 * 128;
  float* wfc2  = wfc1 + 128 * 512;
  char* regA = (char*)(wfc2 + 512 * 128);
  u16* tbuf   = (u16*)regA;
  u16* aobuf  = (u16*)regA;
  u16* mbuf   = (u16*)regA;
  char* regB = regA + (size_t)MWIN * CH * 2;
  u16*   qkvbuf = (u16*)regB;
  float* x1buf  = (float*)regB;
  char* regC = regB + (size_t)MWIN * 384 * 2;
  u16* hbuf = (u16*)regC;

  fuse_all_kernel<<<768, 256, 0, stream>>>(
      qkv_w, qkv_la, qkv_lb, proj_w, proj_la, proj_lb,
      fc1_w, fc1_la, fc1_lb, fc2_w, fc2_la, fc2_lb, wqkv);

  ln1_gather_kernel<<<MWIN / 4, 256, 0, stream>>>(x, prompts, n1g, n1b, tbuf);

  gemm_kernel<128, 384, 0><<<dim3(MWIN / 128, 6), 256, 0, stream>>>(
      tbuf, wqkv, qkv_b, nullptr, nullptr, qkvbuf);

  attn_kernel<<<BWIN * NHEADS, 256, 0, stream>>>(qkvbuf, rpb, aobuf);

  gemm_kernel<128, 128, 1><<<dim3(MPIX / 128, 2), 256, 0, stream>>>(
      aobuf, wproj, proj_b, x, x1buf, nullptr);

  ln2_kernel<<<MPIX / 4, 256, 0, stream>>>(x1buf, n2g, n2b, mbuf);

  gemm_kernel<128, 512, 2><<<dim3(MPIX / 128, 8), 256, 0, stream>>>(
      mbuf, wfc1, fc1_b, nullptr, nullptr, hbuf);

  gemm_kernel<512, 128, 3><<<dim3(MPIX / 128, 2), 256, 0, stream>>>(
      hbuf, wfc2, fc2_b, x1buf, (float*)d_out, nullptr);
}

// Round 3
// 355.433 us; speedup vs baseline: 2.4754x; 2.4754x over previous
//
#include <hip/hip_runtime.h>

typedef unsigned short u16;
typedef unsigned int   u32;
typedef short bf16x8 __attribute__((ext_vector_type(8)));
typedef float f32x4  __attribute__((ext_vector_type(4)));

#define HIMG 56
#define WIMG 56
#define CH   128
#define NHEADS 4
#define WSZ  7
#define SSH  3
#define PP   10
#define HIDD 512
#define NWIN 49          // window tokens
#define NTOK 59          // P + NWIN
#define BWIN 2048        // B * NW
#define DH   32          // head dim
#define KS   36          // padded LDS stride for attn (breaks 32-bank aliasing)
#define MWIN 120832      // BWIN * NTOK
#define MPIX 100352      // B * 56 * 56

__device__ __forceinline__ u16 f2b(float f) {
  u32 u = __float_as_uint(f);
  u += 0x7fffu + ((u >> 16) & 1u);
  return (u16)(u >> 16);
}
__device__ __forceinline__ float blo(u32 w) { return __uint_as_float(w << 16); }
__device__ __forceinline__ float bhi(u32 w) { return __uint_as_float(w & 0xffff0000u); }

// ---------------------------------------------------------------------------
// Fold LoRA (rank 4, scale 1.0) into effective weights and store TRANSPOSED
// bf16: wT[n*K + k] so the GEMM B-operand is contiguous along K.
// Layout: [qkvT 384x128 | projT 128x128 | fc1T 512x128 | fc2T 128x512]
// ---------------------------------------------------------------------------
__global__ void fuse_all_kernel(
    const float* __restrict__ qw,  const float* __restrict__ qa,  const float* __restrict__ qb,
    const float* __restrict__ pw,  const float* __restrict__ pa,  const float* __restrict__ pb,
    const float* __restrict__ f1w, const float* __restrict__ f1a, const float* __restrict__ f1b,
    const float* __restrict__ f2w, const float* __restrict__ f2a, const float* __restrict__ f2b2,
    u16* __restrict__ out)
{
  int idx = blockIdx.x * 256 + threadIdx.x;
  if (idx >= 196608) return;
  const float *w, *la, *lb; int Nc, K, base;
  if (idx < 49152)       { w = qw;  la = qa;  lb = qb;   Nc = 384; K = 128; base = 0; }
  else if (idx < 65536)  { w = pw;  la = pa;  lb = pb;   Nc = 128; K = 128; base = 49152; }
  else if (idx < 131072) { w = f1w; la = f1a; lb = f1b;  Nc = 512; K = 128; base = 65536; }
  else                   { w = f2w; la = f2a; lb = f2b2; Nc = 128; K = 512; base = 131072; }
  const int li = idx - base;
  const int k = li / Nc, n = li - k * Nc;
  float s = w[li];
  #pragma unroll
  for (int r = 0; r < 4; ++r) s += la[k * 4 + r] * lb[r * Nc + n];
  out[base + n * K + k] = f2b(s);
}

// ---------------------------------------------------------------------------
// LN1 + roll(-3,-3) + window partition + prompt concat  ->  t (MWIN x 128) bf16
// ---------------------------------------------------------------------------
__global__ __launch_bounds__(256) void ln1_gather_kernel(
    const float* __restrict__ x, const float* __restrict__ prompts,
    const float* __restrict__ g, const float* __restrict__ bb,
    u16* __restrict__ t)
{
  const int tok  = blockIdx.x * 4 + (threadIdx.x >> 6);
  const int lane = threadIdx.x & 63;
  const int b_ = tok / NTOK, n = tok - b_ * NTOK;
  u32* dst = (u32*)(t + (size_t)tok * CH) + lane;
  if (n < PP) {
    const int b = b_ >> 6;
    const float2 v = *(const float2*)(prompts + ((size_t)b * PP + n) * CH + lane * 2);
    *dst = (u32)f2b(v.x) | ((u32)f2b(v.y) << 16);
    return;
  }
  const int w  = b_ & 63;
  const int wi = n - PP;
  const int hr = (w >> 3) * WSZ + wi / WSZ;
  const int wc = (w & 7) * WSZ + wi % WSZ;
  const int hs  = (hr + SSH) % HIMG;
  const int ws2 = (wc + SSH) % WIMG;
  const float2 v = *(const float2*)(x + ((size_t)(b_ >> 6) * (HIMG * WIMG) + hs * WIMG + ws2) * CH + lane * 2);
  float s = v.x + v.y, s2 = v.x * v.x + v.y * v.y;
  #pragma unroll
  for (int o = 32; o > 0; o >>= 1) { s += __shfl_xor(s, o); s2 += __shfl_xor(s2, o); }
  const float mean = s * (1.0f / CH);
  const float inv  = rsqrtf(s2 * (1.0f / CH) - mean * mean + 1e-5f);
  const float2 gg = *(const float2*)(g  + lane * 2);
  const float2 bv = *(const float2*)(bb + lane * 2);
  const float o0 = (v.x - mean) * inv * gg.x + bv.x;
  const float o1 = (v.y - mean) * inv * gg.y + bv.y;
  *dst = (u32)f2b(o0) | ((u32)f2b(o1) << 16);
}

// ---------------------------------------------------------------------------
// LN2: x1 (fp32) -> m (bf16)
// ---------------------------------------------------------------------------
__global__ __launch_bounds__(256) void ln2_kernel(
    const float* __restrict__ x1, const float* __restrict__ g,
    const float* __restrict__ bb, u16* __restrict__ out)
{
  const int tok  = blockIdx.x * 4 + (threadIdx.x >> 6);
  const int lane = threadIdx.x & 63;
  const float2 v = *(const float2*)(x1 + (size_t)tok * CH + lane * 2);
  float s = v.x + v.y, s2 = v.x * v.x + v.y * v.y;
  #pragma unroll
  for (int o = 32; o > 0; o >>= 1) { s += __shfl_xor(s, o); s2 += __shfl_xor(s2, o); }
  const float mean = s * (1.0f / CH);
  const float inv  = rsqrtf(s2 * (1.0f / CH) - mean * mean + 1e-5f);
  const float2 gg = *(const float2*)(g  + lane * 2);
  const float2 bv = *(const float2*)(bb + lane * 2);
  const float o0 = (v.x - mean) * inv * gg.x + bv.x;
  const float o1 = (v.y - mean) * inv * gg.y + bv.y;
  u32* dst = (u32*)(out + (size_t)tok * CH) + lane;
  *dst = (u32)f2b(o0) | ((u32)f2b(o1) << 16);
}

// ---------------------------------------------------------------------------
// MFMA bf16 GEMM: C[M,NCOLT] = A[M,KTOT] * WT[NCOLT,KTOT]^T + bias, + epilogue
// 128x128 tile, BK=64, 256 threads = 4 waves (2x2), each wave 64x64 out.
// mfma_f32_16x16x32_bf16; A/B frag: row/col = lane&15, k = (lane>>4)*8+j.
// LDS tiles [128][64] bf16, linear dest for global_load_lds; XOR swizzle
// (slot ^= row&7) applied on BOTH the pre-swizzled global source and ds_read.
// MODE 0: bf16 store (qkv)   MODE 2: exact GELU -> bf16 (fc1)
// MODE 1: window-reverse + unroll + residual -> f32 (proj)
// MODE 3: + residual -> f32 (fc2 -> d_out)
// ---------------------------------------------------------------------------
template<int KTOT, int NCOLT, int MODE>
__global__ __launch_bounds__(256) void gemm_kernel(
    const u16* __restrict__ A, const u16* __restrict__ WT,
    const float* __restrict__ bias, const float* __restrict__ aux,
    float* __restrict__ outf, u16* __restrict__ outb)
{
  __shared__ u16 lds_a[128 * 64];
  __shared__ u16 lds_b[128 * 64];
  const int tid  = threadIdx.x;
  const int wv   = tid >> 6, lane = tid & 63;
  const int lr   = lane & 15, lk = lane >> 4;
  const int wrow = wv >> 1, wcol = wv & 1;
  const long rowbase = (long)blockIdx.x * 128;
  const int  colbase = blockIdx.y * 128;

  f32x4 acc[4][4];
  #pragma unroll
  for (int m = 0; m < 4; ++m)
    #pragma unroll
    for (int n = 0; n < 4; ++n)
      acc[m][n] = (f32x4){0.f, 0.f, 0.f, 0.f};

  for (int kb = 0; kb < KTOT; kb += 64) {
    // ---- stage A,B tiles: 1024 chunks of 16B each, swizzled source ----
    #pragma unroll
    for (int it = 0; it < 4; ++it) {
      const int c  = wv * 256 + it * 64 + lane;     // chunk id
      const int r  = c >> 3;                        // tile row
      const int s  = c & 7;                         // 16B slot in row
      const int k8 = s ^ (r & 7);                   // inverse-swizzled source slot
      const u16* ga = A  + (rowbase + r) * KTOT + kb + k8 * 8;
      const u16* gb = WT + (long)(colbase + r) * KTOT + kb + k8 * 8;
      __builtin_amdgcn_global_load_lds((const void*)ga, (void*)&lds_a[(wv * 256 + it * 64) * 8], 16, 0, 0);
      __builtin_amdgcn_global_load_lds((const void*)gb, (void*)&lds_b[(wv * 256 + it * 64) * 8], 16, 0, 0);
    }
    __syncthreads();

    const char* la = (const char*)lds_a;
    const char* lb = (const char*)lds_b;
    #pragma unroll
    for (int k32 = 0; k32 < 2; ++k32) {
      bf16x8 af[4], bfv[4];
      #pragma unroll
      for (int m = 0; m < 4; ++m) {
        const int r = wrow * 64 + m * 16 + lr;
        const int slot = k32 * 4 + lk;
        af[m] = *(const bf16x8*)(la + r * 128 + ((slot ^ (r & 7)) << 4));
      }
      #pragma unroll
      for (int n = 0; n < 4; ++n) {
        const int r = wcol * 64 + n * 16 + lr;
        const int slot = k32 * 4 + lk;
        bfv[n] = *(const bf16x8*)(lb + r * 128 + ((slot ^ (r & 7)) << 4));
      }
      #pragma unroll
      for (int m = 0; m < 4; ++m)
        #pragma unroll
        for (int n = 0; n < 4; ++n)
          acc[m][n] = __builtin_amdgcn_mfma_f32_16x16x32_bf16(af[m], bfv[n], acc[m][n], 0, 0, 0);
    }
    __syncthreads();
  }

  // ---- epilogue ----
  #pragma unroll
  for (int n = 0; n < 4; ++n) {
    const int col = colbase + wcol * 64 + n * 16 + lr;
    const float bs = bias[col];
    #pragma unroll
    for (int m = 0; m < 4; ++m) {
      #pragma unroll
      for (int j = 0; j < 4; ++j) {
        const long row = rowbase + wrow * 64 + m * 16 + lk * 4 + j;
        float v = acc[m][n][j] + bs;
        if (MODE == 0) {
          outb[row * NCOLT + col] = f2b(v);
        } else if (MODE == 2) {
          v = 0.5f * v * (1.f + erff(v * 0.70710678118654752f));
          outb[row * NCOLT + col] = f2b(v);
        } else if (MODE == 1) {
          const int mi = (int)row;
          const int b_ = mi / NWIN, wi = mi - b_ * NWIN;
          const int w  = b_ & 63;
          const int hr = (w >> 3) * WSZ + wi / WSZ;
          const int wc2 = (w & 7) * WSZ + wi % WSZ;
          const int hf = (hr + SSH) % HIMG;
          const int wf = (wc2 + SSH) % WIMG;
          const long o = ((long)(b_ >> 6) * (HIMG * WIMG) + hf * WIMG + wf) * CH + col;
          outf[o] = v + aux[o];
        } else {
          const long o = row * CH + col;
          outf[o] = v + aux[o];
        }
      }
    }
  }
}

// ---------------------------------------------------------------------------
// Fused window attention: one block per (window, head).
// LDS strides padded to 36 floats -> bank = (4*row + d) % 32, conflict-free.
// ---------------------------------------------------------------------------
__global__ __launch_bounds__(256) void attn_kernel(
    const u16* __restrict__ qkv, const float* __restrict__ rpb,
    u16* __restrict__ attn_out)
{
  __shared__ float q_s[NWIN][KS];
  __shared__ float k_s[NTOK][KS];
  __shared__ float v_s[NTOK][KS];
  __shared__ float S[NWIN][NTOK + 1];
  const int blk = blockIdx.x;
  const int b_ = blk >> 2;
  const int h  = blk & 3;
  const int tid = threadIdx.x;
  const u16* base = qkv + (long)b_ * NTOK * 384 + h * DH;

  for (int idx = tid; idx < NTOK * 4; idx += 256) {
    const int n = idx >> 2, d8 = (idx & 3) * 8;
    const u16* p = base + (long)n * 384;
    const uint4 kv = *(const uint4*)(p + 128 + d8);
    const uint4 vv = *(const uint4*)(p + 256 + d8);
    const u32* kw = (const u32*)&kv; const u32* vw = (const u32*)&vv;
    #pragma unroll
    for (int t2 = 0; t2 < 4; ++t2) {
      k_s[n][d8 + t2 * 2]     = blo(kw[t2]);
      k_s[n][d8 + t2 * 2 + 1] = bhi(kw[t2]);
      v_s[n][d8 + t2 * 2]     = blo(vw[t2]);
      v_s[n][d8 + t2 * 2 + 1] = bhi(vw[t2]);
    }
    if (n >= PP) {
      const uint4 qv = *(const uint4*)(p + d8);
      const u32* qw = (const u32*)&qv;
      #pragma unroll
      for (int t2 = 0; t2 < 4; ++t2) {
        q_s[n - PP][d8 + t2 * 2]     = blo(qw[t2]);
        q_s[n - PP][d8 + t2 * 2 + 1] = bhi(qw[t2]);
      }
    }
  }
  __syncthreads();

  const int w  = b_ & 63;
  const int wh = w >> 3, ww = w & 7;
  const float scale = 0.17677669529663687f;   // 32^-0.5
  for (int idx = tid; idx < NWIN * NTOK; idx += 256) {
    const int i = idx / NTOK, j = idx - i * NTOK;
    float s = 0.f;
    #pragma unroll
    for (int d0 = 0; d0 < DH; d0 += 4) {
      const float4 qa = *(const float4*)&q_s[i][d0];
      const float4 kb = *(const float4*)&k_s[j][d0];
      s += qa.x * kb.x + qa.y * kb.y + qa.z * kb.z + qa.w * kb.w;
    }
    s *= scale;
    if (j >= PP) {
      const int jw = j - PP;
      const int ih = i / 7, iw2 = i - ih * 7, jh = jw / 7, jw2 = jw - jh * 7;
      s += rpb[((ih - jh + 6) * 13 + (iw2 - jw2 + 6)) * NHEADS + h];
      const int mi = 3 * ((wh == 7) ? (ih < 4 ? 1 : 2) : 0) + ((ww == 7) ? (iw2 < 4 ? 1 : 2) : 0);
      const int mj = 3 * ((wh == 7) ? (jh < 4 ? 1 : 2) : 0) + ((ww == 7) ? (jw2 < 4 ? 1 : 2) : 0);
      if (mi != mj) s -= 100.f;
    }
    S[i][j] = s;
  }
  __syncthreads();

  if (tid < NWIN * 4) {
    const int i = tid >> 2, qq = tid & 3;
    float mx = -1e30f;
    for (int j = qq; j < NTOK; j += 4) mx = fmaxf(mx, S[i][j]);
    mx = fmaxf(mx, __shfl_xor(mx, 1));
    mx = fmaxf(mx, __shfl_xor(mx, 2));
    float sum = 0.f;
    for (int j = qq; j < NTOK; j += 4) { const float e = __expf(S[i][j] - mx); S[i][j] = e; sum += e; }
    sum += __shfl_xor(sum, 1);
    sum += __shfl_xor(sum, 2);
    const float inv = 1.0f / sum;
    for (int j = qq; j < NTOK; j += 4) S[i][j] *= inv;
  }
  __syncthreads();

  for (int idx = tid; idx < NWIN * 8; idx += 256) {
    const int i = idx >> 3, d4 = (idx & 7) * 4;
    float4 o = make_float4(0.f, 0.f, 0.f, 0.f);
    for (int j = 0; j < NTOK; ++j) {
      const float sv = S[i][j];
      const float4 vv = *(const float4*)&v_s[j][d4];
      o.x += sv * vv.x; o.y += sv * vv.y; o.z += sv * vv.z; o.w += sv * vv.w;
    }
    u16* dst = attn_out + ((long)b_ * NWIN + i) * CH + h * DH + d4;
    *(ushort4*)dst = make_ushort4(f2b(o.x), f2b(o.y), f2b(o.z), f2b(o.w));
  }
}

// ---------------------------------------------------------------------------
extern "C" void kernel_launch(void* const* d_in, const int* in_sizes, int n_in,
                              void* d_out, int out_size, void* d_ws, size_t ws_size,
                              hipStream_t stream)
{
  const float* x       = (const float*)d_in[0];
  const float* prompts = (const float*)d_in[1];
  const float* n1g     = (const float*)d_in[2];
  const float* n1b     = (const float*)d_in[3];
  const float* qkv_w   = (const float*)d_in[4];
  const float* qkv_b   = (const float*)d_in[5];
  const float* qkv_la  = (const float*)d_in[6];
  const float* qkv_lb  = (const float*)d_in[7];
  const float* rpb     = (const float*)d_in[8];
  const float* proj_w  = (const float*)d_in[9];
  const float* proj_b  = (const float*)d_in[10];
  const float* proj_la = (const float*)d_in[11];
  const float* proj_lb = (const float*)d_in[12];
  const float* n2g     = (const float*)d_in[13];
  const float* n2b     = (const float*)d_in[14];
  const float* fc1_w   = (const float*)d_in[15];
  const float* fc1_b   = (const float*)d_in[16];
  const float* fc1_la  = (const float*)d_in[17];
  const float* fc1_lb  = (const float*)d_in[18];
  const float* fc2_w   = (const float*)d_in[19];
  const float* fc2_b   = (const float*)d_in[20];
  const float* fc2_la  = (const float*)d_in[21];
  const float* fc2_lb  = (const float*)d_in[22];

  // workspace: [wT bf16 196608] | regA | regB | regC  (regions reused)
  char* ws = (char*)d_ws;
  u16* wT     = (u16*)ws;
  u16* wqkvT  = wT;
  u16* wprojT = wT + 49152;
  u16* wfc1T  = wT + 65536;
  u16* wfc2T  = wT + 131072;
  char* regA = (char*)(wT + 196608);
  u16* tbuf   = (u16*)regA;          // MWIN*128 bf16
  u16* aobuf  = (u16*)regA;          // MPIX*128 bf16
  u16* mbuf   = (u16*)regA;          // MPIX*128 bf16
  char* regB = regA + (size_t)MWIN * CH * 2;
  u16*   qkvbuf = (u16*)regB;        // MWIN*384 bf16
  float* x1buf  = (float*)regB;      // MPIX*128 f32
  char* regC = regB + (size_t)MWIN * 384 * 2;
  u16* hbuf = (u16*)regC;            // MPIX*512 bf16

  fuse_all_kernel<<<768, 256, 0, stream>>>(
      qkv_w, qkv_la, qkv_lb, proj_w, proj_la, proj_lb,
      fc1_w, fc1_la, fc1_lb, fc2_w, fc2_la, fc2_lb, wT);

  ln1_gather_kernel<<<MWIN / 4, 256, 0, stream>>>(x, prompts, n1g, n1b, tbuf);

  gemm_kernel<128, 384, 0><<<dim3(MWIN / 128, 3), 256, 0, stream>>>(
      tbuf, wqkvT, qkv_b, nullptr, nullptr, qkvbuf);

  attn_kernel<<<BWIN * NHEADS, 256, 0, stream>>>(qkvbuf, rpb, aobuf);

  gemm_kernel<128, 128, 1><<<dim3(MPIX / 128, 1), 256, 0, stream>>>(
      aobuf, wprojT, proj_b, x, x1buf, nullptr);

  ln2_kernel<<<MPIX / 4, 256, 0, stream>>>(x1buf, n2g, n2b, mbuf);

  gemm_kernel<128, 512, 2><<<dim3(MPIX / 128, 4), 256, 0, stream>>>(
      mbuf, wfc1T, fc1_b, nullptr, nullptr, hbuf);

  gemm_kernel<512, 128, 3><<<dim3(MPIX / 128, 1), 256, 0, stream>>>(
      hbuf, wfc2T, fc2_b, x1buf, (float*)d_out, nullptr);
}

// Round 4
// 260.180 us; speedup vs baseline: 3.3817x; 1.3661x over previous
//
#include <hip/hip_runtime.h>

typedef unsigned short u16;
typedef unsigned int   u32;
typedef short bf16x8 __attribute__((ext_vector_type(8)));
typedef short bf16x4 __attribute__((ext_vector_type(4)));
typedef float f32x4  __attribute__((ext_vector_type(4)));

#define HIMG 56
#define WIMG 56
#define CH   128
#define NHEADS 4
#define WSZ  7
#define SSH  3
#define PP   10
#define HIDD 512
#define NWIN 49          // window tokens
#define NTOK 59          // P + NWIN
#define BWIN 2048        // B * NW
#define DH   32          // head dim
#define MWIN 120832      // BWIN * NTOK
#define MPIX 100352      // B * 56 * 56
#define SLDS 68          // padded u16 stride for attn P-tile (8B aligned rows)

__device__ __forceinline__ u16 f2b(float f) {
  u32 u = __float_as_uint(f);
  u += 0x7fffu + ((u >> 16) & 1u);
  return (u16)(u >> 16);
}
__device__ __forceinline__ float blo(u32 w) { return __uint_as_float(w << 16); }
__device__ __forceinline__ float bhi(u32 w) { return __uint_as_float(w & 0xffff0000u); }

// ---------------------------------------------------------------------------
// Fold LoRA into effective weights, store TRANSPOSED bf16 (K-contiguous).
// ---------------------------------------------------------------------------
__global__ void fuse_all_kernel(
    const float* __restrict__ qw,  const float* __restrict__ qa,  const float* __restrict__ qb,
    const float* __restrict__ pw,  const float* __restrict__ pa,  const float* __restrict__ pb,
    const float* __restrict__ f1w, const float* __restrict__ f1a, const float* __restrict__ f1b,
    const float* __restrict__ f2w, const float* __restrict__ f2a, const float* __restrict__ f2b2,
    u16* __restrict__ out)
{
  int idx = blockIdx.x * 256 + threadIdx.x;
  if (idx >= 196608) return;
  const float *w, *la, *lb; int Nc, K, base;
  if (idx < 49152)       { w = qw;  la = qa;  lb = qb;   Nc = 384; K = 128; base = 0; }
  else if (idx < 65536)  { w = pw;  la = pa;  lb = pb;   Nc = 128; K = 128; base = 49152; }
  else if (idx < 131072) { w = f1w; la = f1a; lb = f1b;  Nc = 512; K = 128; base = 65536; }
  else                   { w = f2w; la = f2a; lb = f2b2; Nc = 128; K = 512; base = 131072; }
  const int li = idx - base;
  const int k = li / Nc, n = li - k * Nc;
  float s = w[li];
  #pragma unroll
  for (int r = 0; r < 4; ++r) s += la[k * 4 + r] * lb[r * Nc + n];
  out[base + n * K + k] = f2b(s);
}

// ---------------------------------------------------------------------------
// Precompute bias+mask table bm[type][h][64][64] f32:
//   type = (wh==7)*2 + (ww==7).  j>=59 -> -1e30 (pad mask), j<10 -> 0 (prompt),
//   else rel-pos bias + (-100 shift mask).  i>=49 rows -> 0 (unused, finite).
// ---------------------------------------------------------------------------
__global__ void bm_kernel(const float* __restrict__ rpb, float* __restrict__ bm)
{
  const int idx = blockIdx.x * 256 + threadIdx.x;   // 65536
  const int j = idx & 63, i = (idx >> 6) & 63, h = (idx >> 12) & 3, type = idx >> 14;
  float v = 0.f;
  if (i < 49) {
    if (j >= 59) v = -1e30f;
    else if (j >= PP) {
      const int jw = j - PP;
      const int ih = i / 7, iw = i - ih * 7, jh = jw / 7, jw2 = jw - jh * 7;
      v = rpb[((ih - jh + 6) * 13 + (iw - jw2 + 6)) * NHEADS + h];
      const int wh7 = type >> 1, ww7 = type & 1;
      const int mi = 3 * (wh7 ? (ih < 4 ? 1 : 2) : 0) + (ww7 ? (iw < 4 ? 1 : 2) : 0);
      const int mj = 3 * (wh7 ? (jh < 4 ? 1 : 2) : 0) + (ww7 ? (jw2 < 4 ? 1 : 2) : 0);
      if (mi != mj) v -= 100.f;
    }
  }
  bm[idx] = v;
}

// ---------------------------------------------------------------------------
// LN1 + roll(-3,-3) + window partition + prompt concat  ->  t (MWIN x 128) bf16
// ---------------------------------------------------------------------------
__global__ __launch_bounds__(256) void ln1_gather_kernel(
    const float* __restrict__ x, const float* __restrict__ prompts,
    const float* __restrict__ g, const float* __restrict__ bb,
    u16* __restrict__ t)
{
  const int tok  = blockIdx.x * 4 + (threadIdx.x >> 6);
  const int lane = threadIdx.x & 63;
  const int b_ = tok / NTOK, n = tok - b_ * NTOK;
  u32* dst = (u32*)(t + (size_t)tok * CH) + lane;
  if (n < PP) {
    const int b = b_ >> 6;
    const float2 v = *(const float2*)(prompts + ((size_t)b * PP + n) * CH + lane * 2);
    *dst = (u32)f2b(v.x) | ((u32)f2b(v.y) << 16);
    return;
  }
  const int w  = b_ & 63;
  const int wi = n - PP;
  const int hr = (w >> 3) * WSZ + wi / WSZ;
  const int wc = (w & 7) * WSZ + wi % WSZ;
  const int hs  = (hr + SSH) % HIMG;
  const int ws2 = (wc + SSH) % WIMG;
  const float2 v = *(const float2*)(x + ((size_t)(b_ >> 6) * (HIMG * WIMG) + hs * WIMG + ws2) * CH + lane * 2);
  float s = v.x + v.y, s2 = v.x * v.x + v.y * v.y;
  #pragma unroll
  for (int o = 32; o > 0; o >>= 1) { s += __shfl_xor(s, o); s2 += __shfl_xor(s2, o); }
  const float mean = s * (1.0f / CH);
  const float inv  = rsqrtf(s2 * (1.0f / CH) - mean * mean + 1e-5f);
  const float2 gg = *(const float2*)(g  + lane * 2);
  const float2 bv = *(const float2*)(bb + lane * 2);
  const float o0 = (v.x - mean) * inv * gg.x + bv.x;
  const float o1 = (v.y - mean) * inv * gg.y + bv.y;
  *dst = (u32)f2b(o0) | ((u32)f2b(o1) << 16);
}

// ---------------------------------------------------------------------------
// LN2: x1 (fp32) -> m (bf16)
// ---------------------------------------------------------------------------
__global__ __launch_bounds__(256) void ln2_kernel(
    const float* __restrict__ x1, const float* __restrict__ g,
    const float* __restrict__ bb, u16* __restrict__ out)
{
  const int tok  = blockIdx.x * 4 + (threadIdx.x >> 6);
  const int lane = threadIdx.x & 63;
  const float2 v = *(const float2*)(x1 + (size_t)tok * CH + lane * 2);
  float s = v.x + v.y, s2 = v.x * v.x + v.y * v.y;
  #pragma unroll
  for (int o = 32; o > 0; o >>= 1) { s += __shfl_xor(s, o); s2 += __shfl_xor(s2, o); }
  const float mean = s * (1.0f / CH);
  const float inv  = rsqrtf(s2 * (1.0f / CH) - mean * mean + 1e-5f);
  const float2 gg = *(const float2*)(g  + lane * 2);
  const float2 bv = *(const float2*)(bb + lane * 2);
  const float o0 = (v.x - mean) * inv * gg.x + bv.x;
  const float o1 = (v.y - mean) * inv * gg.y + bv.y;
  u32* dst = (u32*)(out + (size_t)tok * CH) + lane;
  *dst = (u32)f2b(o0) | ((u32)f2b(o1) << 16);
}

// ---------------------------------------------------------------------------
// MFMA bf16 GEMM (unchanged from R3, validated): 128x128 tile, BK=64, 4 waves.
// ---------------------------------------------------------------------------
template<int KTOT, int NCOLT, int MODE>
__global__ __launch_bounds__(256) void gemm_kernel(
    const u16* __restrict__ A, const u16* __restrict__ WT,
    const float* __restrict__ bias, const float* __restrict__ aux,
    float* __restrict__ outf, u16* __restrict__ outb)
{
  __shared__ u16 lds_a[128 * 64];
  __shared__ u16 lds_b[128 * 64];
  const int tid  = threadIdx.x;
  const int wv   = tid >> 6, lane = tid & 63;
  const int lr   = lane & 15, lk = lane >> 4;
  const int wrow = wv >> 1, wcol = wv & 1;
  const long rowbase = (long)blockIdx.x * 128;
  const int  colbase = blockIdx.y * 128;

  f32x4 acc[4][4];
  #pragma unroll
  for (int m = 0; m < 4; ++m)
    #pragma unroll
    for (int n = 0; n < 4; ++n)
      acc[m][n] = (f32x4){0.f, 0.f, 0.f, 0.f};

  for (int kb = 0; kb < KTOT; kb += 64) {
    #pragma unroll
    for (int it = 0; it < 4; ++it) {
      const int c  = wv * 256 + it * 64 + lane;
      const int r  = c >> 3;
      const int s  = c & 7;
      const int k8 = s ^ (r & 7);
      const u16* ga = A  + (rowbase + r) * KTOT + kb + k8 * 8;
      const u16* gb = WT + (long)(colbase + r) * KTOT + kb + k8 * 8;
      __builtin_amdgcn_global_load_lds((const void*)ga, (void*)&lds_a[(wv * 256 + it * 64) * 8], 16, 0, 0);
      __builtin_amdgcn_global_load_lds((const void*)gb, (void*)&lds_b[(wv * 256 + it * 64) * 8], 16, 0, 0);
    }
    __syncthreads();

    const char* la = (const char*)lds_a;
    const char* lb = (const char*)lds_b;
    #pragma unroll
    for (int k32 = 0; k32 < 2; ++k32) {
      bf16x8 af[4], bfv[4];
      #pragma unroll
      for (int m = 0; m < 4; ++m) {
        const int r = wrow * 64 + m * 16 + lr;
        const int slot = k32 * 4 + lk;
        af[m] = *(const bf16x8*)(la + r * 128 + ((slot ^ (r & 7)) << 4));
      }
      #pragma unroll
      for (int n = 0; n < 4; ++n) {
        const int r = wcol * 64 + n * 16 + lr;
        const int slot = k32 * 4 + lk;
        bfv[n] = *(const bf16x8*)(lb + r * 128 + ((slot ^ (r & 7)) << 4));
      }
      #pragma unroll
      for (int m = 0; m < 4; ++m)
        #pragma unroll
        for (int n = 0; n < 4; ++n)
          acc[m][n] = __builtin_amdgcn_mfma_f32_16x16x32_bf16(af[m], bfv[n], acc[m][n], 0, 0, 0);
    }
    __syncthreads();
  }

  #pragma unroll
  for (int n = 0; n < 4; ++n) {
    const int col = colbase + wcol * 64 + n * 16 + lr;
    const float bs = bias[col];
    #pragma unroll
    for (int m = 0; m < 4; ++m) {
      #pragma unroll
      for (int j = 0; j < 4; ++j) {
        const long row = rowbase + wrow * 64 + m * 16 + lk * 4 + j;
        float v = acc[m][n][j] + bs;
        if (MODE == 0) {
          outb[row * NCOLT + col] = f2b(v);
        } else if (MODE == 2) {
          v = 0.5f * v * (1.f + erff(v * 0.70710678118654752f));
          outb[row * NCOLT + col] = f2b(v);
        } else if (MODE == 1) {
          const int mi = (int)row;
          const int b_ = mi / NWIN, wi = mi - b_ * NWIN;
          const int w  = b_ & 63;
          const int hr = (w >> 3) * WSZ + wi / WSZ;
          const int wc2 = (w & 7) * WSZ + wi % WSZ;
          const int hf = (hr + SSH) % HIMG;
          const int wf = (wc2 + SSH) % WIMG;
          const long o = ((long)(b_ >> 6) * (HIMG * WIMG) + hf * WIMG + wf) * CH + col;
          outf[o] = v + aux[o];
        } else {
          const long o = row * CH + col;
          outf[o] = v + aux[o];
        }
      }
    }
  }
}

// ---------------------------------------------------------------------------
// MFMA window attention. One block = one window; wave w = head w.
// S^T = mfma(K, Q): C-layout col = query i (lane&15), row = key j.
// Softmax over j: 16 in-lane values + shfl_xor(16,32); 1/sum folded in-lane.
// P -> LDS [i][j] (b64 writes, stride 68 u16), PV = mfma(P_lds, V_gather).
// ---------------------------------------------------------------------------
__global__ __launch_bounds__(256) void attn_mfma_kernel(
    const u16* __restrict__ qkv, const float* __restrict__ bm,
    u16* __restrict__ attn_out)
{
  __shared__ u16 s_lds[NHEADS][64][SLDS];
  const int tid  = threadIdx.x;
  const int h    = tid >> 6, lane = tid & 63;
  const int lr   = lane & 15, lk = lane >> 4;
  const int b_   = blockIdx.x;
  const u16* base = qkv + (size_t)b_ * NTOK * 384;
  const int w    = b_ & 63;
  const int type = (((w >> 3) == 7) ? 2 : 0) + (((w & 7) == 7) ? 1 : 0);
  const float scale = 0.17677669529663687f;   // 32^-0.5

  // ---- QK^T (swapped): A = K (rows = keys), B = Q (cols = queries) ----
  bf16x8 kf[4], qf[4];
  #pragma unroll
  for (int t4 = 0; t4 < 4; ++t4) {
    int tj = t4 * 16 + lr; if (tj > 58) tj = 58;
    kf[t4] = *(const bf16x8*)(base + (size_t)tj * 384 + 128 + h * DH + lk * 8);
    int ti = PP + t4 * 16 + lr; if (ti > 58) ti = 58;
    qf[t4] = *(const bf16x8*)(base + (size_t)ti * 384 + h * DH + lk * 8);
  }
  f32x4 sacc[4][4];   // [mtj][nti]
  #pragma unroll
  for (int a = 0; a < 4; ++a)
    #pragma unroll
    for (int b = 0; b < 4; ++b)
      sacc[a][b] = (f32x4){0.f, 0.f, 0.f, 0.f};
  #pragma unroll
  for (int mtj = 0; mtj < 4; ++mtj)
    #pragma unroll
    for (int nti = 0; nti < 4; ++nti)
      sacc[mtj][nti] = __builtin_amdgcn_mfma_f32_16x16x32_bf16(kf[mtj], qf[nti], sacc[mtj][nti], 0, 0, 0);

  // ---- bias/mask + softmax over j (per query i = nti*16+lr) ----
  const float* bmh = bm + (size_t)(type * NHEADS + h) * 64 * 64;
  #pragma unroll
  for (int nti = 0; nti < 4; ++nti) {
    const int i = nti * 16 + lr;
    float sv[16];
    #pragma unroll
    for (int mtj = 0; mtj < 4; ++mtj) {
      const float4 bmv = *(const float4*)(bmh + i * 64 + mtj * 16 + lk * 4);
      sv[mtj * 4 + 0] = sacc[mtj][nti][0] * scale + bmv.x;
      sv[mtj * 4 + 1] = sacc[mtj][nti][1] * scale + bmv.y;
      sv[mtj * 4 + 2] = sacc[mtj][nti][2] * scale + bmv.z;
      sv[mtj * 4 + 3] = sacc[mtj][nti][3] * scale + bmv.w;
    }
    float mx = sv[0];
    #pragma unroll
    for (int t = 1; t < 16; ++t) mx = fmaxf(mx, sv[t]);
    mx = fmaxf(mx, __shfl_xor(mx, 16));
    mx = fmaxf(mx, __shfl_xor(mx, 32));
    float sum = 0.f;
    #pragma unroll
    for (int t = 0; t < 16; ++t) { sv[t] = __expf(sv[t] - mx); sum += sv[t]; }
    sum += __shfl_xor(sum, 16);
    sum += __shfl_xor(sum, 32);
    const float inv = 1.0f / sum;
    #pragma unroll
    for (int mtj = 0; mtj < 4; ++mtj) {
      const ushort4 pk = make_ushort4(f2b(sv[mtj * 4 + 0] * inv), f2b(sv[mtj * 4 + 1] * inv),
                                      f2b(sv[mtj * 4 + 2] * inv), f2b(sv[mtj * 4 + 3] * inv));
      *(ushort4*)&s_lds[h][i][mtj * 16 + lk * 4] = pk;
    }
  }
  __syncthreads();

  // ---- PV: out[i][d] = sum_j P[i][j] V[j][d] ----
  f32x4 oacc[4][2];
  #pragma unroll
  for (int a = 0; a < 4; ++a) { oacc[a][0] = (f32x4){0,0,0,0}; oacc[a][1] = (f32x4){0,0,0,0}; }
  #pragma unroll
  for (int ks = 0; ks < 2; ++ks) {
    bf16x8 pa[4];
    #pragma unroll
    for (int mt = 0; mt < 4; ++mt) {
      const u16* pr = &s_lds[h][mt * 16 + lr][ks * 32 + lk * 8];
      const bf16x4 lo = *(const bf16x4*)pr;
      const bf16x4 hi = *(const bf16x4*)(pr + 4);
      pa[mt] = __builtin_shufflevector(lo, hi, 0, 1, 2, 3, 4, 5, 6, 7);
    }
    bf16x8 bv[2];
    #pragma unroll
    for (int nd = 0; nd < 2; ++nd) {
      const u16* vb = base + 256 + h * DH + nd * 16 + lr;
      #pragma unroll
      for (int jj = 0; jj < 8; ++jj) {
        int jc = ks * 32 + lk * 8 + jj; if (jc > 58) jc = 58;
        bv[nd][jj] = (short)vb[(size_t)jc * 384];
      }
    }
    #pragma unroll
    for (int mt = 0; mt < 4; ++mt)
      #pragma unroll
      for (int nd = 0; nd < 2; ++nd)
        oacc[mt][nd] = __builtin_amdgcn_mfma_f32_16x16x32_bf16(pa[mt], bv[nd], oacc[mt][nd], 0, 0, 0);
  }

  // ---- store out rows i<49: attn_out[(b*49+i)*128 + h*32 + d] ----
  #pragma unroll
  for (int mt = 0; mt < 4; ++mt)
    #pragma unroll
    for (int reg = 0; reg < 4; ++reg) {
      const int i = mt * 16 + lk * 4 + reg;
      if (i < 49) {
        u16* dst = attn_out + ((size_t)b_ * NWIN + i) * CH + h * DH + lr;
        dst[0]  = f2b(oacc[mt][0][reg]);
        dst[16] = f2b(oacc[mt][1][reg]);
      }
    }
}

// ---------------------------------------------------------------------------
extern "C" void kernel_launch(void* const* d_in, const int* in_sizes, int n_in,
                              void* d_out, int out_size, void* d_ws, size_t ws_size,
                              hipStream_t stream)
{
  const float* x       = (const float*)d_in[0];
  const float* prompts = (const float*)d_in[1];
  const float* n1g     = (const float*)d_in[2];
  const float* n1b     = (const float*)d_in[3];
  const float* qkv_w   = (const float*)d_in[4];
  const float* qkv_b   = (const float*)d_in[5];
  const float* qkv_la  = (const float*)d_in[6];
  const float* qkv_lb  = (const float*)d_in[7];
  const float* rpb     = (const float*)d_in[8];
  const float* proj_w  = (const float*)d_in[9];
  const float* proj_b  = (const float*)d_in[10];
  const float* proj_la = (const float*)d_in[11];
  const float* proj_lb = (const float*)d_in[12];
  const float* n2g     = (const float*)d_in[13];
  const float* n2b     = (const float*)d_in[14];
  const float* fc1_w   = (const float*)d_in[15];
  const float* fc1_b   = (const float*)d_in[16];
  const float* fc1_la  = (const float*)d_in[17];
  const float* fc1_lb  = (const float*)d_in[18];
  const float* fc2_w   = (const float*)d_in[19];
  const float* fc2_b   = (const float*)d_in[20];
  const float* fc2_la  = (const float*)d_in[21];
  const float* fc2_lb  = (const float*)d_in[22];

  // workspace: [wT bf16 196608 | bm f32 65536] | regA | regB | regC
  char* ws = (char*)d_ws;
  u16* wT     = (u16*)ws;
  u16* wqkvT  = wT;
  u16* wprojT = wT + 49152;
  u16* wfc1T  = wT + 65536;
  u16* wfc2T  = wT + 131072;
  float* bm   = (float*)(ws + 393216);
  char* regA = ws + 393216 + 262144;
  u16* tbuf   = (u16*)regA;          // MWIN*128 bf16
  u16* aobuf  = (u16*)regA;          // MPIX*128 bf16
  u16* mbuf   = (u16*)regA;          // MPIX*128 bf16
  char* regB = regA + (size_t)MWIN * CH * 2;
  u16*   qkvbuf = (u16*)regB;        // MWIN*384 bf16
  float* x1buf  = (float*)regB;      // MPIX*128 f32
  char* regC = regB + (size_t)MWIN * 384 * 2;
  u16* hbuf = (u16*)regC;            // MPIX*512 bf16

  fuse_all_kernel<<<768, 256, 0, stream>>>(
      qkv_w, qkv_la, qkv_lb, proj_w, proj_la, proj_lb,
      fc1_w, fc1_la, fc1_lb, fc2_w, fc2_la, fc2_lb, wT);

  bm_kernel<<<256, 256, 0, stream>>>(rpb, bm);

  ln1_gather_kernel<<<MWIN / 4, 256, 0, stream>>>(x, prompts, n1g, n1b, tbuf);

  gemm_kernel<128, 384, 0><<<dim3(MWIN / 128, 3), 256, 0, stream>>>(
      tbuf, wqkvT, qkv_b, nullptr, nullptr, qkvbuf);

  attn_mfma_kernel<<<BWIN, 256, 0, stream>>>(qkvbuf, bm, aobuf);

  gemm_kernel<128, 128, 1><<<dim3(MPIX / 128, 1), 256, 0, stream>>>(
      aobuf, wprojT, proj_b, x, x1buf, nullptr);

  ln2_kernel<<<MPIX / 4, 256, 0, stream>>>(x1buf, n2g, n2b, mbuf);

  gemm_kernel<128, 512, 2><<<dim3(MPIX / 128, 4), 256, 0, stream>>>(
      mbuf, wfc1T, fc1_b, nullptr, nullptr, hbuf);

  gemm_kernel<512, 128, 3><<<dim3(MPIX / 128, 1), 256, 0, stream>>>(
      hbuf, wfc2T, fc2_b, x1buf, (float*)d_out, nullptr);
}